// Round 11
// baseline (1850.382 us; speedup 1.0000x reference)
//
#include <hip/hip_runtime.h>
#include <math.h>

#define NB 2048
#define NS 100
#define NF 158
#define ND 512
#define NH 8

typedef unsigned short u16;
typedef __attribute__((ext_vector_type(8))) short bf16x8;
typedef __attribute__((ext_vector_type(8))) unsigned short u16x8;
typedef __attribute__((ext_vector_type(4))) float f32x4;

__device__ __forceinline__ u16 f2bf(float f) {
    union { float f; unsigned u; } v; v.f = f;
    unsigned u = v.u;
    return (u16)((u + 0x7fffu + ((u >> 16) & 1u)) >> 16);   // RNE
}

__device__ __forceinline__ float bf2f(u16 v) {
    union { unsigned u; float f; } x; x.u = ((unsigned)v) << 16; return x.f;
}

__device__ __forceinline__ void gload16(const void* g, void* l) {
    __builtin_amdgcn_global_load_lds(
        (const __attribute__((address_space(1))) unsigned*)g,
        (__attribute__((address_space(3))) unsigned*)l, 16, 0, 0);
}

// 8 f32 -> bf16x8 with tail guard at NF (src rows 8B aligned -> float2)
__device__ __forceinline__ bf16x8 load8_cvt(const float* __restrict__ base, int c0) {
    bf16x8 r;
    if (c0 + 8 <= NF) {
        #pragma unroll
        for (int j = 0; j < 8; j += 2) {
            float2 v = *(const float2*)(base + c0 + j);
            r[j] = (short)f2bf(v.x); r[j + 1] = (short)f2bf(v.y);
        }
    } else {
        #pragma unroll
        for (int j = 0; j < 8; ++j)
            r[j] = (c0 + j < NF) ? (short)f2bf(base[c0 + j]) : (short)0;
    }
    return r;
}

// ---------------------------------------------------------------------------
// prep_w: folded QKV weights -> MFMA-B-fragment layout.
// sel in {0(q),1(k)}: head-dim PERMUTED mapping d = 4*l16 + ni (S invariant);
// sel==2(v): natural mapping.
// ---------------------------------------------------------------------------
__global__ __launch_bounds__(256) void prep_w_kernel(
    const float* __restrict__ Wq, const float* __restrict__ Wk,
    const float* __restrict__ Wv, const float* __restrict__ Wfeat,
    u16* __restrict__ Wf)
{
    int bid = blockIdx.x;           // 0..1535
    int sel = bid >> 9;
    int n = bid & 511;
    const float* Wsrc = (sel == 0) ? Wq : (sel == 1) ? Wk : Wv;
    __shared__ float wrow[ND];
    int t = threadIdx.x;
    wrow[t] = Wsrc[(size_t)n * ND + t];
    wrow[t + 256] = Wsrc[(size_t)n * ND + t + 256];
    __syncthreads();
    if (t < 160) {
        float acc = 0.f;
        if (t < NF)
            for (int d = 0; d < ND; ++d)
                acc += wrow[d] * Wfeat[(size_t)d * NF + t];
        int h = n >> 6, local = n & 63;
        int ni, l16;
        if (sel < 2) { ni = local & 3; l16 = local >> 2; }       // permuted
        else         { ni = (local >> 4) & 3; l16 = local & 15; } // natural
        int ks = t >> 5, quad = (t >> 3) & 3, j = t & 7;
        size_t idx = (((((size_t)sel * 8 + h) * 4 + ni) * 5 + ks) * 64
                      + (quad << 4) + l16) * 8 + j;
        Wf[idx] = f2bf(acc);
    }
}

// ---------------------------------------------------------------------------
// prep_c: T4[(sel*8+h)*100+s][idx64] = (b_feat+pe[s])@W[n,:]+b[n]
// ---------------------------------------------------------------------------
__global__ __launch_bounds__(256) void prep_c_kernel(
    const float* __restrict__ Wq, const float* __restrict__ Wk, const float* __restrict__ Wv,
    const float* __restrict__ bq, const float* __restrict__ bk, const float* __restrict__ bv,
    const float* __restrict__ bfeat, const float* __restrict__ pe,
    float* __restrict__ T4)
{
    int bid = blockIdx.x;           // 0..299
    int sel = bid / 100;
    int s = bid - sel * 100;
    const float* Wsrc = (sel == 0) ? Wq : (sel == 1) ? Wk : Wv;
    const float* bsrc = (sel == 0) ? bq : (sel == 1) ? bk : bv;
    __shared__ float xv[ND];
    int t = threadIdx.x;
    xv[t] = bfeat[t] + pe[(size_t)s * ND + t];
    xv[t + 256] = bfeat[t + 256] + pe[(size_t)s * ND + t + 256];
    __syncthreads();
    #pragma unroll
    for (int rr = 0; rr < 2; ++rr) {
        int r = t + (rr << 8);
        const float* wr = Wsrc + (size_t)r * ND;
        float acc = bsrc[r];
        for (int d = 0; d < ND; d += 4) {
            float4 w4 = *(const float4*)(wr + d);
            acc += w4.x * xv[d] + w4.y * xv[d+1] + w4.z * xv[d+2] + w4.w * xv[d+3];
        }
        int h = r >> 6, local = r & 63;
        int idx64 = (sel < 2) ? local : (((local & 15) << 2) | (local >> 4));
        T4[(((size_t)(sel * 8 + h)) * 100 + s) * 64 + idx64] = acc;
    }
}

// ---------------------------------------------------------------------------
__global__ __launch_bounds__(256) void pad_cast_kernel(
    const float* __restrict__ src, u16* __restrict__ dst,
    int R, int C, int Cp, int total)
{
    int idx = blockIdx.x * 256 + threadIdx.x;
    if (idx >= total) return;
    int r = idx / Cp, c = idx - r * Cp;
    float v = (r < R && c < C) ? src[(size_t)r * C + c] : 0.f;
    dst[idx] = f2bf(v);
}

__global__ __launch_bounds__(256) void pad_b1_kernel(
    const float* __restrict__ b1, float* __restrict__ b1p)
{
    int t = threadIdx.x;
    b1p[t] = (t < NF) ? b1[t] : 0.f;
}

// ---------------------------------------------------------------------------
// FUSED QKV + attention, 512 threads (8 waves x 16 rows).
// LDS repack (R11): Q[128x76] + Ks[112x68] + Vt[64x136] = 50.9 KB, with
// P[128x134] ALIASED over Q+Ks (both dead after S; P written post-barrier).
// 52.1 KB < 160/3 -> 3 blocks/CU (24 waves/CU). Math identical to R10.
// Note: Ks pad rows (100-111) removed — S cols 100..111 are unconditionally
// REPLACED with -3e38 before softmax, so their MFMA inputs never propagate.
// ---------------------------------------------------------------------------
#define LDQ 76      // Q row stride (shorts)
#define LDK 68      // Ks row stride (shorts)
#define LDV 136     // Vt row stride (shorts)
#define LDP 134     // P row stride (shorts)
#define OFF_K (128 * LDQ)
#define OFF_V (128 * LDQ + 112 * LDK)

__global__ __launch_bounds__(512, 6) void qkv_attn_kernel(
    const float* __restrict__ src, const u16* __restrict__ Wf,
    const float* __restrict__ T4, u16* __restrict__ O)
{
    __shared__ short LB[128 * LDQ + 112 * LDK + 64 * LDV];
    short* Qs = LB;             // 128 rows, stride 76
    short* KS = LB + OFF_K;     // 112 rows, stride 68 (rows >=100 unused garbage)
    short* VT = LB + OFF_V;     // 64 rows, stride 136
    short* P  = LB;             // 128 rows, stride 134 (aliases Qs+KS)

    int t = threadIdx.x;
    int lane = t & 63, wave = t >> 6;       // wave 0..7
    int quad = lane >> 4, l16 = lane & 15;
    int rows0 = wave << 4;                  // this wave's 16 rows
    int b = blockIdx.x;
    const float* xb = src + (size_t)b * NS * NF;
    const size_t rowbase = (size_t)b * NS;
    f32x4 z = {0.f, 0.f, 0.f, 0.f};

    // static zero pad: Vt keys 100..127 (needed: P=0 x NaN guard).
    // Region is NOT aliased by P (P extent 34304B < OFF_V*2B) -> write once.
    for (int l = t; l < 64 * 28; l += 512) {
        int d = l / 28, s = 100 + (l - d * 28);
        VT[d * LDV + s] = 0;
    }

    // X A-fragments for this wave's 16 rows (rows >= 100 -> zero), in VGPRs
    int arow = rows0 + l16;
    bf16x8 AF[5];
    {
        const float* xr = xb + (size_t)arow * NF;
        #pragma unroll
        for (int ks = 0; ks < 5; ++ks) {
            if (arow < NS) AF[ks] = load8_cvt(xr, (ks << 5) + (quad << 3));
            else { bf16x8 zz = {0,0,0,0,0,0,0,0}; AF[ks] = zz; }
        }
    }
    __syncthreads();   // Vt pads visible before first head's PV

    for (int h = 0; h < NH; ++h) {
        // ---- q/k/v for head h (this wave: 16 rows x 64 head-dims)
        #pragma unroll
        for (int sel = 0; sel < 3; ++sel) {
            f32x4 acc[4];
            #pragma unroll
            for (int ni = 0; ni < 4; ++ni) acc[ni] = z;
            #pragma unroll
            for (int ks = 0; ks < 5; ++ks) {
                bf16x8 wfr[4];
                #pragma unroll
                for (int ni = 0; ni < 4; ++ni)
                    wfr[ni] = *(const bf16x8*)(Wf +
                        (((((size_t)sel * 8 + h) * 4 + ni) * 5 + ks) * 64 + lane) * 8);
                #pragma unroll
                for (int ni = 0; ni < 4; ++ni)
                    acc[ni] = __builtin_amdgcn_mfma_f32_16x16x32_bf16(
                        AF[ks], wfr[ni], acc[ni], 0, 0, 0);
            }
            // epilogue: +T4, bf16 -> LDS
            #pragma unroll
            for (int r = 0; r < 4; ++r) {
                int row_s = rows0 + (quad << 2) + r;
                bool real = row_s < NS;
                float4 tv = make_float4(0.f, 0.f, 0.f, 0.f);
                if (real)
                    tv = *(const float4*)(T4 +
                        (((size_t)(sel * 8 + h)) * 100 + row_s) * 64 + (l16 << 2));
                if (sel < 2) {
                    // permuted: lane holds dims 4*l16..4*l16+3 -> one b64 write
                    ushort4 pk;
                    pk.x = f2bf(acc[0][r] + tv.x);
                    pk.y = f2bf(acc[1][r] + tv.y);
                    pk.z = f2bf(acc[2][r] + tv.z);
                    pk.w = f2bf(acc[3][r] + tv.w);
                    if (sel == 0) *(ushort4*)&Qs[row_s * LDQ + (l16 << 2)] = pk;  // Q (pad rows = 0)
                    else if (real) *(ushort4*)&KS[row_s * LDK + (l16 << 2)] = pk;
                } else {
                    float tvs[4] = {tv.x, tv.y, tv.z, tv.w};
                    #pragma unroll
                    for (int ni = 0; ni < 4; ++ni) {
                        int nloc = (ni << 4) + l16;
                        float v = acc[ni][r] + tvs[ni];
                        if (real) VT[nloc * LDV + row_s] = (short)f2bf(v);
                    }
                }
            }
        }
        __syncthreads();

        // ---- S = Q K^T  (1 row-tile x 7 col-tiles per wave, K=64 permuted dims)
        f32x4 sc[7];
        #pragma unroll
        for (int ni = 0; ni < 7; ++ni) sc[ni] = z;
        #pragma unroll
        for (int ks = 0; ks < 2; ++ks) {
            bf16x8 aq = *(const bf16x8*)&Qs[(rows0 + l16) * LDQ + (ks << 5) + (quad << 3)];
            bf16x8 bk[7];
            #pragma unroll
            for (int ni = 0; ni < 7; ++ni)
                bk[ni] = *(const bf16x8*)&KS[((ni << 4) + l16) * LDK + (ks << 5) + (quad << 3)];
            #pragma unroll
            for (int ni = 0; ni < 7; ++ni)
                sc[ni] = __builtin_amdgcn_mfma_f32_16x16x32_bf16(aq, bk[ni], sc[ni], 0, 0, 0);
        }
        __syncthreads();   // all waves done reading Q/Ks before P overwrites them

        // ---- softmax in registers; P (bf16) into alias region, stride 134
        #pragma unroll
        for (int r = 0; r < 4; ++r) {
            if (l16 >= 4) sc[6][r] = -3.0e38f;   // cols 100..111 masked (REPLACED)
            float mx = sc[0][r];
            #pragma unroll
            for (int ni = 1; ni < 7; ++ni) mx = fmaxf(mx, sc[ni][r]);
            #pragma unroll
            for (int off = 1; off < 16; off <<= 1) mx = fmaxf(mx, __shfl_xor(mx, off));
            float sum = 0.f;
            #pragma unroll
            for (int ni = 0; ni < 7; ++ni) {
                float e = expf((sc[ni][r] - mx) * 0.125f);
                sc[ni][r] = e; sum += e;
            }
            #pragma unroll
            for (int off = 1; off < 16; off <<= 1) sum += __shfl_xor(sum, off);
            float inv = 1.f / sum;
            int row = rows0 + (quad << 2) + r;
            #pragma unroll
            for (int ni = 0; ni < 7; ++ni)
                P[row * LDP + (ni << 4) + l16] = (short)f2bf(sc[ni][r] * inv);
            P[row * LDP + 112 + l16] = 0;        // zero K-pad cols 112..127
        }
        __syncthreads();

        // ---- O = P V  (K=128)
        f32x4 oa[4];
        #pragma unroll
        for (int ni = 0; ni < 4; ++ni) oa[ni] = z;
        #pragma unroll
        for (int ks = 0; ks < 4; ++ks) {
            bf16x8 ap = *(const bf16x8*)&P[(rows0 + l16) * LDP + (ks << 5) + (quad << 3)];
            bf16x8 bv[4];
            #pragma unroll
            for (int ni = 0; ni < 4; ++ni)
                bv[ni] = *(const bf16x8*)&VT[((ni << 4) + l16) * LDV + (ks << 5) + (quad << 3)];
            #pragma unroll
            for (int ni = 0; ni < 4; ++ni)
                oa[ni] = __builtin_amdgcn_mfma_f32_16x16x32_bf16(ap, bv[ni], oa[ni], 0, 0, 0);
        }
        #pragma unroll
        for (int r = 0; r < 4; ++r) {
            int row = rows0 + (quad << 2) + r;
            if (row < NS) {
                u16* orow = O + (rowbase + row) * 512 + (h << 6);
                #pragma unroll
                for (int ni = 0; ni < 4; ++ni)
                    orow[(ni << 4) + l16] = f2bf(oa[ni][r]);
            }
        }
        __syncthreads();   // before next head rewrites Qs/KS/VT (over P)
    }
}

// ---------------------------------------------------------------------------
// Generic bf16 GEMM (used for FFN1): 128x128 tile, BK=32.
// ---------------------------------------------------------------------------
template<int OUTMODE, bool RELU>
__global__ __launch_bounds__(256) void gemm_bf16(
    const u16* __restrict__ A, const u16* __restrict__ W,
    const float* __restrict__ bias, void* __restrict__ Cv, int K, int ldc)
{
    __shared__ short As[128 * 32];
    __shared__ short Bs[128 * 32];
    int t = threadIdx.x;
    int lane = t & 63, wave = t >> 6;
    int quad = lane >> 4, l16 = lane & 15;
    int wr = wave >> 1, wc = wave & 1;
    int m0 = blockIdx.y << 7, n0 = blockIdx.x << 7;

    f32x4 acc[4][4];
    f32x4 z = {0.f, 0.f, 0.f, 0.f};
    #pragma unroll
    for (int mi = 0; mi < 4; ++mi)
        #pragma unroll
        for (int ni = 0; ni < 4; ++ni) acc[mi][ni] = z;

    int rowA = t >> 2;
    int cch = (t & 3) << 3;
    const u16* aSrc0 = A + (size_t)(m0 + rowA) * K + cch;
    const u16* aSrc1 = A + (size_t)(m0 + rowA + 64) * K + cch;
    const u16* bSrc0 = W + (size_t)(n0 + rowA) * K + cch;
    const u16* bSrc1 = W + (size_t)(n0 + rowA + 64) * K + cch;
    short* aDst0 = As + t * 8;
    short* aDst1 = As + (t + 256) * 8;
    short* bDst0 = Bs + t * 8;
    short* bDst1 = Bs + (t + 256) * 8;

    int nk = K >> 5;
    for (int kc = 0; kc < nk; ++kc) {
        if (kc) __syncthreads();
        gload16(aSrc0, aDst0);
        gload16(aSrc1, aDst1);
        gload16(bSrc0, bDst0);
        gload16(bSrc1, bDst1);
        aSrc0 += 32; aSrc1 += 32; bSrc0 += 32; bSrc1 += 32;
        __syncthreads();

        bf16x8 af[4], bw[4];
        #pragma unroll
        for (int mi = 0; mi < 4; ++mi)
            af[mi] = *(const bf16x8*)(As + ((size_t)((wr << 6) + (mi << 4) + l16) * 32 + (quad << 3)));
        #pragma unroll
        for (int ni = 0; ni < 4; ++ni)
            bw[ni] = *(const bf16x8*)(Bs + ((size_t)((wc << 6) + (ni << 4) + l16) * 32 + (quad << 3)));
        #pragma unroll
        for (int mi = 0; mi < 4; ++mi)
            #pragma unroll
            for (int ni = 0; ni < 4; ++ni)
                acc[mi][ni] = __builtin_amdgcn_mfma_f32_16x16x32_bf16(af[mi], bw[ni], acc[mi][ni], 0, 0, 0);
    }

    #pragma unroll
    for (int mi = 0; mi < 4; ++mi) {
        #pragma unroll
        for (int r = 0; r < 4; ++r) {
            int row = m0 + (wr << 6) + (mi << 4) + (quad << 2) + r;
            #pragma unroll
            for (int ni = 0; ni < 4; ++ni) {
                int col = n0 + (wc << 6) + (ni << 4) + l16;
                float v = acc[mi][ni][r];
                if (bias) v += bias[col];
                if (RELU) v = fmaxf(v, 0.f);
                if (OUTMODE == 0)
                    ((float*)Cv)[(size_t)row * ldc + col] = v;
                else
                    ((u16*)Cv)[(size_t)row * ldc + col] = f2bf(v);
            }
        }
    }
}

// ---------------------------------------------------------------------------
// Fused GEMM + add-LayerNorm epilogue (proven R6-R10).
// ---------------------------------------------------------------------------
template<int OUTMODE>
__global__ __launch_bounds__(512, 2) void gemm_ln(
    const u16* __restrict__ A, const u16* __restrict__ W,
    const float* __restrict__ bias, const float* __restrict__ lnw,
    const float* __restrict__ lnb, void* __restrict__ outv, int K)
{
    __shared__ short As[64 * 32];
    __shared__ short Bs[512 * 32];
    __shared__ float red_s[64][9];
    __shared__ float red_q[64][9];
    __shared__ float mrow[64], rrow[64];

    int t = threadIdx.x;
    int lane = t & 63, wave = t >> 6;
    int quad = lane >> 4, l16 = lane & 15;
    int m0 = blockIdx.x << 6;

    f32x4 acc[4][4];
    f32x4 z = {0.f, 0.f, 0.f, 0.f};
    #pragma unroll
    for (int mi = 0; mi < 4; ++mi)
        #pragma unroll
        for (int ni = 0; ni < 4; ++ni) acc[mi][ni] = z;

    int koff = (t & 3) << 3;
    const u16* aSrc = A + (size_t)(m0 + (t >> 2)) * K + koff;
    const u16* bSrc0 = W + (size_t)(t >> 2) * K + koff;
    const u16* bSrc1 = W + (size_t)((t >> 2) + 128) * K + koff;
    const u16* bSrc2 = W + (size_t)((t >> 2) + 256) * K + koff;
    const u16* bSrc3 = W + (size_t)((t >> 2) + 384) * K + koff;
    short* aDst = As + t * 8;
    short* bDst0 = Bs + t * 8;
    short* bDst1 = Bs + (t + 512) * 8;
    short* bDst2 = Bs + (t + 1024) * 8;
    short* bDst3 = Bs + (t + 1536) * 8;

    int nk = K >> 5;
    for (int kc = 0; kc < nk; ++kc) {
        if (kc) __syncthreads();
        if (t < 256) gload16(aSrc, aDst);
        gload16(bSrc0, bDst0);
        gload16(bSrc1, bDst1);
        gload16(bSrc2, bDst2);
        gload16(bSrc3, bDst3);
        aSrc += 32; bSrc0 += 32; bSrc1 += 32; bSrc2 += 32; bSrc3 += 32;
        __syncthreads();

        bf16x8 af[4], bw[4];
        #pragma unroll
        for (int mi = 0; mi < 4; ++mi)
            af[mi] = *(const bf16x8*)(As + ((mi << 4) + l16) * 32 + (quad << 3));
        #pragma unroll
        for (int ni = 0; ni < 4; ++ni)
            bw[ni] = *(const bf16x8*)(Bs + ((wave << 6) + (ni << 4) + l16) * 32 + (quad << 3));
        #pragma unroll
        for (int mi = 0; mi < 4; ++mi)
            #pragma unroll
            for (int ni = 0; ni < 4; ++ni)
                acc[mi][ni] = __builtin_amdgcn_mfma_f32_16x16x32_bf16(af[mi], bw[ni], acc[mi][ni], 0, 0, 0);
    }

    float lwv[4], lbv[4];
    #pragma unroll
    for (int ni = 0; ni < 4; ++ni) {
        int col = (wave << 6) + (ni << 4) + l16;
        float bv = bias[col];
        lwv[ni] = lnw[col];
        lbv[ni] = lnb[col];
        #pragma unroll
        for (int mi = 0; mi < 4; ++mi)
            #pragma unroll
            for (int r = 0; r < 4; ++r) acc[mi][ni][r] += bv;
    }
    #pragma unroll
    for (int mi = 0; mi < 4; ++mi) {
        #pragma unroll
        for (int r = 0; r < 4; ++r) {
            float s = acc[mi][0][r] + acc[mi][1][r] + acc[mi][2][r] + acc[mi][3][r];
            float q = acc[mi][0][r]*acc[mi][0][r] + acc[mi][1][r]*acc[mi][1][r]
                    + acc[mi][2][r]*acc[mi][2][r] + acc[mi][3][r]*acc[mi][3][r];
            #pragma unroll
            for (int off = 1; off < 16; off <<= 1) {
                s += __shfl_xor(s, off);
                q += __shfl_xor(q, off);
            }
            if (l16 == 0) {
                int row = (mi << 4) + (quad << 2) + r;
                red_s[row][wave] = s;
                red_q[row][wave] = q;
            }
        }
    }
    __syncthreads();
    if (t < 64) {
        float s = 0.f, q = 0.f;
        #pragma unroll
        for (int w8 = 0; w8 < 8; ++w8) { s += red_s[t][w8]; q += red_q[t][w8]; }
        float mean = s * (1.f / 512.f);
        float var = q * (1.f / 512.f) - mean * mean;
        mrow[t] = mean;
        rrow[t] = rsqrtf(var + 1e-5f);
    }
    __syncthreads();
    #pragma unroll
    for (int mi = 0; mi < 4; ++mi) {
        #pragma unroll
        for (int r = 0; r < 4; ++r) {
            int lrow = (mi << 4) + (quad << 2) + r;
            float mean = mrow[lrow], rstd = rrow[lrow];
            size_t grow = (size_t)(m0 + lrow) * 512;
            #pragma unroll
            for (int ni = 0; ni < 4; ++ni) {
                int col = (wave << 6) + (ni << 4) + l16;
                float v = acc[mi][ni][r];
                float y = v + (v - mean) * rstd * lwv[ni] + lbv[ni];
                if (OUTMODE == 0) ((float*)outv)[grow + col] = y;
                else ((u16*)outv)[grow + col] = f2bf(y);
            }
        }
    }
}

// ---------------------------------------------------------------------------
// u_stage1: T1[b,r] = dot(Wt[r,:], Y2[b, last, :])    (Y2 bf16)
// ---------------------------------------------------------------------------
__global__ __launch_bounds__(256) void u_stage1_kernel(
    const u16* __restrict__ Y2, const float* __restrict__ Wt,
    float* __restrict__ T1)
{
    __shared__ float yl[16][512];
    int t = threadIdx.x;
    int r0 = blockIdx.x << 6;
    int bg = blockIdx.y << 4;
    for (int l = t; l < 1024; l += 256) {
        int bb = l >> 6, seg = (l & 63) << 3;
        u16x8 v = *(const u16x8*)&Y2[((size_t)(bg + bb) * NS + 99) * ND + seg];
        #pragma unroll
        for (int j = 0; j < 8; ++j) yl[bb][seg + j] = bf2f(v[j]);
    }
    __syncthreads();
    int r = r0 + (t & 63);
    int b0 = t >> 6;
    const float* wr = Wt + (size_t)r * ND;
    float acc[4] = {0.f, 0.f, 0.f, 0.f};
    for (int d = 0; d < ND; d += 4) {
        float4 w4 = *(const float4*)(wr + d);
        #pragma unroll
        for (int bb = 0; bb < 4; ++bb) {
            int bl = (b0 << 2) + bb;
            acc[bb] += w4.x * yl[bl][d] + w4.y * yl[bl][d+1]
                     + w4.z * yl[bl][d+2] + w4.w * yl[bl][d+3];
        }
    }
    #pragma unroll
    for (int bb = 0; bb < 4; ++bb)
        T1[(size_t)(bg + (b0 << 2) + bb) * ND + r] = acc[bb];
}

__global__ __launch_bounds__(256) void u_stage2_kernel(
    const float* __restrict__ T1, const float* __restrict__ Wt,
    float* __restrict__ U)
{
    __shared__ float t1s[16][512];
    int t = threadIdx.x;
    int c0 = blockIdx.x << 6;
    int bg = blockIdx.y << 4;
    for (int l = t; l < 2048; l += 256) {
        int bb = l >> 7, seg = (l & 127) << 2;
        *(float4*)&t1s[bb][seg] = *(const float4*)&T1[(size_t)(bg + bb) * ND + seg];
    }
    __syncthreads();
    int c = c0 + (t & 63);
    int b0 = t >> 6;
    float acc[4] = {0.f, 0.f, 0.f, 0.f};
    for (int r = 0; r < ND; ++r) {
        float w = Wt[(size_t)r * ND + c];
        #pragma unroll
        for (int bb = 0; bb < 4; ++bb)
            acc[bb] += w * t1s[(b0 << 2) + bb][r];
    }
    #pragma unroll
    for (int bb = 0; bb < 4; ++bb)
        U[(size_t)(bg + (b0 << 2) + bb) * ND + c] = acc[bb];
}

// ---------------------------------------------------------------------------
// pool (Y2 bf16)
// ---------------------------------------------------------------------------
__global__ __launch_bounds__(256) void pool_kernel(
    const u16* __restrict__ Y2, const float* __restrict__ U,
    const float* __restrict__ Wout, const float* __restrict__ bout,
    float* __restrict__ out)
{
    __shared__ float u[ND];
    __shared__ float lam[128];
    __shared__ float red[4];
    int t = threadIdx.x;
    int b = blockIdx.x;
    const u16* y2b = Y2 + (size_t)b * NS * ND;
    u[t] = U[(size_t)b * ND + t];
    u[t + 256] = U[(size_t)b * ND + t + 256];
    __syncthreads();
    int wid = t >> 6, lane = t & 63;
    int c0 = lane << 2;
    for (int s = wid; s < NS; s += 4) {
        const u16* yr = y2b + (size_t)s * ND;
        ushort4 q0 = *(const ushort4*)(yr + c0);
        ushort4 q1 = *(const ushort4*)(yr + 256 + c0);
        float a = bf2f(q0.x)*u[c0] + bf2f(q0.y)*u[c0+1] + bf2f(q0.z)*u[c0+2] + bf2f(q0.w)*u[c0+3]
                + bf2f(q1.x)*u[256+c0] + bf2f(q1.y)*u[256+c0+1]
                + bf2f(q1.z)*u[256+c0+2] + bf2f(q1.w)*u[256+c0+3];
        #pragma unroll
        for (int off = 32; off > 0; off >>= 1) a += __shfl_xor(a, off);
        if (lane == 0) lam[s] = a;
    }
    __syncthreads();
    if (t < 64) {
        float l0 = lam[t];
        float l1 = (t + 64 < NS) ? lam[t + 64] : -3.0e38f;
        float mx = fmaxf(l0, l1);
        #pragma unroll
        for (int off = 32; off > 0; off >>= 1) mx = fmaxf(mx, __shfl_xor(mx, off));
        float e0 = expf(l0 - mx);
        float e1 = (t + 64 < NS) ? expf(l1 - mx) : 0.f;
        float ssum = e0 + e1;
        #pragma unroll
        for (int off = 32; off > 0; off >>= 1) ssum += __shfl_xor(ssum, off);
        float inv = 1.f / ssum;
        lam[t] = e0 * inv;
        if (t + 64 < NS) lam[t + 64] = e1 * inv;
    }
    __syncthreads();
    float p0 = 0.f, p1 = 0.f;
    for (int s = 0; s < NS; ++s) {
        float lm = lam[s];
        const u16* yr = y2b + (size_t)s * ND;
        p0 += lm * bf2f(yr[t]);
        p1 += lm * bf2f(yr[t + 256]);
    }
    float vd = p0 * Wout[t] + p1 * Wout[t + 256];
    #pragma unroll
    for (int off = 32; off > 0; off >>= 1) vd += __shfl_xor(vd, off);
    if (lane == 0) red[wid] = vd;
    __syncthreads();
    if (t == 0) out[b] = red[0] + red[1] + red[2] + red[3] + bout[0];
}

// ---------------------------------------------------------------------------
static size_t ws_need(int CBc) {
    size_t cm = (size_t)CBc * NS;
    size_t b = 0;
    b += cm * 512 * 2;         // AO16
    b += cm * 512 * 2;         // Y116
    b += cm * 256 * 2;         // ACT16
    b += cm * 512 * 2;         // Y2 (bf16)
    b += (size_t)CBc * 512 * 4 * 2;  // T1, U
    b += 1536 * 160 * 2;       // Wf
    b += 512 * 512 * 2 + 256 * 512 * 2 + 512 * 256 * 2;
    b += 3 * 8 * 100 * 64 * 4; // T4
    b += 256 * 4;
    b += 64 * 1024;
    return b;
}

extern "C" void kernel_launch(void* const* d_in, const int* in_sizes, int n_in,
                              void* d_out, int out_size, void* d_ws, size_t ws_size,
                              hipStream_t stream)
{
    const float* src   = (const float*)d_in[0];
    const float* Wfeat = (const float*)d_in[1];
    const float* bfeat = (const float*)d_in[2];
    const float* pe    = (const float*)d_in[3];
    const float* Wq    = (const float*)d_in[4];
    const float* bq    = (const float*)d_in[5];
    const float* Wk    = (const float*)d_in[6];
    const float* bk    = (const float*)d_in[7];
    const float* Wv    = (const float*)d_in[8];
    const float* bv    = (const float*)d_in[9];
    const float* Wo    = (const float*)d_in[10];
    const float* bo    = (const float*)d_in[11];
    const float* lnw   = (const float*)d_in[12];
    const float* lnb   = (const float*)d_in[13];
    const float* W1    = (const float*)d_in[14];
    const float* b1    = (const float*)d_in[15];
    const float* W2    = (const float*)d_in[16];
    const float* b2    = (const float*)d_in[17];
    const float* Wt    = (const float*)d_in[18];
    const float* Wout  = (const float*)d_in[19];
    const float* bout  = (const float*)d_in[20];
    float* out = (float*)d_out;

    int CBc = (ws_size >= ws_need(1024)) ? 1024
            : (ws_size >= ws_need(512))  ? 512
            : (ws_size >= ws_need(256))  ? 256 : 128;
    int NCH = NB / CBc;
    size_t CMc = (size_t)CBc * NS;

    char* p = (char*)d_ws;
    auto alloc = [&](size_t bytes) { char* r = p; p += (bytes + 255) & ~(size_t)255; return r; };
    u16*   AO16  = (u16*)  alloc(CMc * 512 * 2);
    u16*   Y116  = (u16*)  alloc(CMc * 512 * 2);
    u16*   ACT16 = (u16*)  alloc(CMc * 256 * 2);
    u16*   Y2    = (u16*)  alloc(CMc * 512 * 2);
    float* T1    = (float*)alloc((size_t)CBc * 512 * 4);
    float* U     = (float*)alloc((size_t)CBc * 512 * 4);
    u16*   Wf    = (u16*)  alloc(1536 * 160 * 2);
    u16*   Wo16  = (u16*)  alloc(512 * 512 * 2);
    u16*   W116  = (u16*)  alloc(256 * 512 * 2);
    u16*   W216  = (u16*)  alloc(512 * 256 * 2);
    float* T4    = (float*)alloc(3 * 8 * 100 * 64 * 4);
    float* b1p   = (float*)alloc(256 * 4);

    prep_w_kernel<<<1536, 256, 0, stream>>>(Wq, Wk, Wv, Wfeat, Wf);
    prep_c_kernel<<<300, 256, 0, stream>>>(Wq, Wk, Wv, bq, bk, bv, bfeat, pe, T4);
    pad_cast_kernel<<<(512 * 512) / 256, 256, 0, stream>>>(Wo, Wo16, 512, 512, 512, 512 * 512);
    pad_cast_kernel<<<(256 * 512) / 256, 256, 0, stream>>>(W1, W116, NF, 512, 512, 256 * 512);
    pad_cast_kernel<<<(512 * 256) / 256, 256, 0, stream>>>(W2, W216, 512, NF, 256, 512 * 256);
    pad_b1_kernel<<<1, 256, 0, stream>>>(b1, b1p);

    dim3 g256(2, CMc / 128);
    dim3 gU(8, CBc / 16);
    int gLN = CMc / 64;

    for (int c = 0; c < NCH; ++c) {
        const float* srcC = src + (size_t)c * CMc * NF;
        float* outC = out + (size_t)c * CBc;

        // fused QKV + attention -> AO16 (bf16), 3 blocks/CU
        qkv_attn_kernel<<<CBc, 512, 0, stream>>>(srcC, Wf, T4, AO16);
        // y1 = (AO16@Wo^T + bo) + LN(...) -> bf16 (fused)
        gemm_ln<1><<<gLN, 512, 0, stream>>>(AO16, Wo16, bo, lnw, lnb, Y116, 512);
        // act = relu(y1 @ W116^T + b1p) -> bf16 [CMc,256]
        gemm_bf16<1, true><<<g256, 256, 0, stream>>>(Y116, W116, b1p, ACT16, 512, 256);
        // y2 = (act@W2^T + b2) + LN(...) -> bf16 (fused)
        gemm_ln<1><<<gLN, 512, 0, stream>>>(ACT16, W216, b2, lnw, lnb, Y2, 256);
        // pooling head
        u_stage1_kernel<<<gU, 256, 0, stream>>>(Y2, Wt, T1);
        u_stage2_kernel<<<gU, 256, 0, stream>>>(T1, Wt, U);
        pool_kernel<<<CBc, 256, 0, stream>>>(Y2, U, Wout, bout, outC);
    }

    (void)in_sizes; (void)n_in; (void)out_size; (void)ws_size;
}

// Round 12
// 1679.521 us; speedup vs baseline: 1.1017x; 1.1017x over previous
//
#include <hip/hip_runtime.h>
#include <math.h>

#define NB 2048
#define NS 100
#define NF 158
#define ND 512
#define NH 8

typedef unsigned short u16;
typedef __attribute__((ext_vector_type(8))) short bf16x8;
typedef __attribute__((ext_vector_type(8))) unsigned short u16x8;
typedef __attribute__((ext_vector_type(4))) float f32x4;

__device__ __forceinline__ u16 f2bf(float f) {
    union { float f; unsigned u; } v; v.f = f;
    unsigned u = v.u;
    return (u16)((u + 0x7fffu + ((u >> 16) & 1u)) >> 16);   // RNE
}

__device__ __forceinline__ float bf2f(u16 v) {
    union { unsigned u; float f; } x; x.u = ((unsigned)v) << 16; return x.f;
}

__device__ __forceinline__ void gload16(const void* g, void* l) {
    __builtin_amdgcn_global_load_lds(
        (const __attribute__((address_space(1))) unsigned*)g,
        (__attribute__((address_space(3))) unsigned*)l, 16, 0, 0);
}

// 8 f32 -> bf16x8 with tail guard at NF (src rows 8B aligned -> float2)
__device__ __forceinline__ bf16x8 load8_cvt(const float* __restrict__ base, int c0) {
    bf16x8 r;
    if (c0 + 8 <= NF) {
        #pragma unroll
        for (int j = 0; j < 8; j += 2) {
            float2 v = *(const float2*)(base + c0 + j);
            r[j] = (short)f2bf(v.x); r[j + 1] = (short)f2bf(v.y);
        }
    } else {
        #pragma unroll
        for (int j = 0; j < 8; ++j)
            r[j] = (c0 + j < NF) ? (short)f2bf(base[c0 + j]) : (short)0;
    }
    return r;
}

// ---------------------------------------------------------------------------
// prep_w: folded QKV weights -> MFMA-B-fragment layout.
// sel in {0(q),1(k)}: head-dim PERMUTED mapping d = 4*l16 + ni (S invariant);
// sel==2(v): natural mapping.
// ---------------------------------------------------------------------------
__global__ __launch_bounds__(256) void prep_w_kernel(
    const float* __restrict__ Wq, const float* __restrict__ Wk,
    const float* __restrict__ Wv, const float* __restrict__ Wfeat,
    u16* __restrict__ Wf)
{
    int bid = blockIdx.x;           // 0..1535
    int sel = bid >> 9;
    int n = bid & 511;
    const float* Wsrc = (sel == 0) ? Wq : (sel == 1) ? Wk : Wv;
    __shared__ float wrow[ND];
    int t = threadIdx.x;
    wrow[t] = Wsrc[(size_t)n * ND + t];
    wrow[t + 256] = Wsrc[(size_t)n * ND + t + 256];
    __syncthreads();
    if (t < 160) {
        float acc = 0.f;
        if (t < NF)
            for (int d = 0; d < ND; ++d)
                acc += wrow[d] * Wfeat[(size_t)d * NF + t];
        int h = n >> 6, local = n & 63;
        int ni, l16;
        if (sel < 2) { ni = local & 3; l16 = local >> 2; }       // permuted
        else         { ni = (local >> 4) & 3; l16 = local & 15; } // natural
        int ks = t >> 5, quad = (t >> 3) & 3, j = t & 7;
        size_t idx = (((((size_t)sel * 8 + h) * 4 + ni) * 5 + ks) * 64
                      + (quad << 4) + l16) * 8 + j;
        Wf[idx] = f2bf(acc);
    }
}

// ---------------------------------------------------------------------------
// prep_c: T4[(sel*8+h)*100+s][idx64] = (b_feat+pe[s])@W[n,:]+b[n]
// ---------------------------------------------------------------------------
__global__ __launch_bounds__(256) void prep_c_kernel(
    const float* __restrict__ Wq, const float* __restrict__ Wk, const float* __restrict__ Wv,
    const float* __restrict__ bq, const float* __restrict__ bk, const float* __restrict__ bv,
    const float* __restrict__ bfeat, const float* __restrict__ pe,
    float* __restrict__ T4)
{
    int bid = blockIdx.x;           // 0..299
    int sel = bid / 100;
    int s = bid - sel * 100;
    const float* Wsrc = (sel == 0) ? Wq : (sel == 1) ? Wk : Wv;
    const float* bsrc = (sel == 0) ? bq : (sel == 1) ? bk : bv;
    __shared__ float xv[ND];
    int t = threadIdx.x;
    xv[t] = bfeat[t] + pe[(size_t)s * ND + t];
    xv[t + 256] = bfeat[t + 256] + pe[(size_t)s * ND + t + 256];
    __syncthreads();
    #pragma unroll
    for (int rr = 0; rr < 2; ++rr) {
        int r = t + (rr << 8);
        const float* wr = Wsrc + (size_t)r * ND;
        float acc = bsrc[r];
        for (int d = 0; d < ND; d += 4) {
            float4 w4 = *(const float4*)(wr + d);
            acc += w4.x * xv[d] + w4.y * xv[d+1] + w4.z * xv[d+2] + w4.w * xv[d+3];
        }
        int h = r >> 6, local = r & 63;
        int idx64 = (sel < 2) ? local : (((local & 15) << 2) | (local >> 4));
        T4[(((size_t)(sel * 8 + h)) * 100 + s) * 64 + idx64] = acc;
    }
}

// ---------------------------------------------------------------------------
__global__ __launch_bounds__(256) void pad_cast_kernel(
    const float* __restrict__ src, u16* __restrict__ dst,
    int R, int C, int Cp, int total)
{
    int idx = blockIdx.x * 256 + threadIdx.x;
    if (idx >= total) return;
    int r = idx / Cp, c = idx - r * Cp;
    float v = (r < R && c < C) ? src[(size_t)r * C + c] : 0.f;
    dst[idx] = f2bf(v);
}

__global__ __launch_bounds__(256) void pad_b1_kernel(
    const float* __restrict__ b1, float* __restrict__ b1p)
{
    int t = threadIdx.x;
    b1p[t] = (t < NF) ? b1[t] : 0.f;
}

// ---------------------------------------------------------------------------
// FUSED QKV + attention, 512 threads (8 waves x 16 rows).
// LDS repack: Q[128x76] + Ks[112x68] + Vt[64x136] = 52.2 KB, with
// P[128x134] ALIASED over Q+Ks (dead after S). 3 blocks/CU from LDS budget.
// launch_bounds(512,4): VGPR cap 128 (body compiles to ~64) — R11's (512,6)
// forced 40 VGPR -> AF-fragment spill -> 190 MB scratch traffic. Reverted.
// ---------------------------------------------------------------------------
#define LDQ 76      // Q row stride (shorts)
#define LDK 68      // Ks row stride (shorts)
#define LDV 136     // Vt row stride (shorts)
#define LDP 134     // P row stride (shorts)
#define OFF_K (128 * LDQ)
#define OFF_V (128 * LDQ + 112 * LDK)

__global__ __launch_bounds__(512, 4) void qkv_attn_kernel(
    const float* __restrict__ src, const u16* __restrict__ Wf,
    const float* __restrict__ T4, u16* __restrict__ O)
{
    __shared__ short LB[128 * LDQ + 112 * LDK + 64 * LDV];
    short* Qs = LB;             // 128 rows, stride 76
    short* KS = LB + OFF_K;     // 112 rows, stride 68 (rows >=100 unused)
    short* VT = LB + OFF_V;     // 64 rows, stride 136
    short* P  = LB;             // 128 rows, stride 134 (aliases Qs+KS)

    int t = threadIdx.x;
    int lane = t & 63, wave = t >> 6;       // wave 0..7
    int quad = lane >> 4, l16 = lane & 15;
    int rows0 = wave << 4;                  // this wave's 16 rows
    int b = blockIdx.x;
    const float* xb = src + (size_t)b * NS * NF;
    const size_t rowbase = (size_t)b * NS;
    f32x4 z = {0.f, 0.f, 0.f, 0.f};

    // static zero pad: Vt keys 100..127 (P=0 x NaN guard). Not P-aliased.
    for (int l = t; l < 64 * 28; l += 512) {
        int d = l / 28, s = 100 + (l - d * 28);
        VT[d * LDV + s] = 0;
    }

    // X A-fragments for this wave's 16 rows (rows >= 100 -> zero), in VGPRs
    int arow = rows0 + l16;
    bf16x8 AF[5];
    {
        const float* xr = xb + (size_t)arow * NF;
        #pragma unroll
        for (int ks = 0; ks < 5; ++ks) {
            if (arow < NS) AF[ks] = load8_cvt(xr, (ks << 5) + (quad << 3));
            else { bf16x8 zz = {0,0,0,0,0,0,0,0}; AF[ks] = zz; }
        }
    }
    __syncthreads();   // Vt pads visible before first head's PV

    for (int h = 0; h < NH; ++h) {
        // ---- q/k/v for head h (this wave: 16 rows x 64 head-dims)
        #pragma unroll
        for (int sel = 0; sel < 3; ++sel) {
            f32x4 acc[4];
            #pragma unroll
            for (int ni = 0; ni < 4; ++ni) acc[ni] = z;
            #pragma unroll
            for (int ks = 0; ks < 5; ++ks) {
                bf16x8 wfr[4];
                #pragma unroll
                for (int ni = 0; ni < 4; ++ni)
                    wfr[ni] = *(const bf16x8*)(Wf +
                        (((((size_t)sel * 8 + h) * 4 + ni) * 5 + ks) * 64 + lane) * 8);
                #pragma unroll
                for (int ni = 0; ni < 4; ++ni)
                    acc[ni] = __builtin_amdgcn_mfma_f32_16x16x32_bf16(
                        AF[ks], wfr[ni], acc[ni], 0, 0, 0);
            }
            // epilogue: +T4, bf16 -> LDS
            #pragma unroll
            for (int r = 0; r < 4; ++r) {
                int row_s = rows0 + (quad << 2) + r;
                bool real = row_s < NS;
                float4 tv = make_float4(0.f, 0.f, 0.f, 0.f);
                if (real)
                    tv = *(const float4*)(T4 +
                        (((size_t)(sel * 8 + h)) * 100 + row_s) * 64 + (l16 << 2));
                if (sel < 2) {
                    ushort4 pk;
                    pk.x = f2bf(acc[0][r] + tv.x);
                    pk.y = f2bf(acc[1][r] + tv.y);
                    pk.z = f2bf(acc[2][r] + tv.z);
                    pk.w = f2bf(acc[3][r] + tv.w);
                    if (sel == 0) *(ushort4*)&Qs[row_s * LDQ + (l16 << 2)] = pk;  // Q (pad rows = 0)
                    else if (real) *(ushort4*)&KS[row_s * LDK + (l16 << 2)] = pk;
                } else {
                    float tvs[4] = {tv.x, tv.y, tv.z, tv.w};
                    #pragma unroll
                    for (int ni = 0; ni < 4; ++ni) {
                        int nloc = (ni << 4) + l16;
                        float v = acc[ni][r] + tvs[ni];
                        if (real) VT[nloc * LDV + row_s] = (short)f2bf(v);
                    }
                }
            }
        }
        __syncthreads();

        // ---- S = Q K^T  (1 row-tile x 7 col-tiles per wave, K=64 permuted dims)
        f32x4 sc[7];
        #pragma unroll
        for (int ni = 0; ni < 7; ++ni) sc[ni] = z;
        #pragma unroll
        for (int ks = 0; ks < 2; ++ks) {
            bf16x8 aq = *(const bf16x8*)&Qs[(rows0 + l16) * LDQ + (ks << 5) + (quad << 3)];
            bf16x8 bk[7];
            #pragma unroll
            for (int ni = 0; ni < 7; ++ni)
                bk[ni] = *(const bf16x8*)&KS[((ni << 4) + l16) * LDK + (ks << 5) + (quad << 3)];
            #pragma unroll
            for (int ni = 0; ni < 7; ++ni)
                sc[ni] = __builtin_amdgcn_mfma_f32_16x16x32_bf16(aq, bk[ni], sc[ni], 0, 0, 0);
        }
        __syncthreads();   // all waves done reading Q/Ks before P overwrites them

        // ---- softmax in registers; P (bf16) into alias region, stride 134
        #pragma unroll
        for (int r = 0; r < 4; ++r) {
            if (l16 >= 4) sc[6][r] = -3.0e38f;   // cols 100..111 masked (REPLACED)
            float mx = sc[0][r];
            #pragma unroll
            for (int ni = 1; ni < 7; ++ni) mx = fmaxf(mx, sc[ni][r]);
            #pragma unroll
            for (int off = 1; off < 16; off <<= 1) mx = fmaxf(mx, __shfl_xor(mx, off));
            float sum = 0.f;
            #pragma unroll
            for (int ni = 0; ni < 7; ++ni) {
                float e = expf((sc[ni][r] - mx) * 0.125f);
                sc[ni][r] = e; sum += e;
            }
            #pragma unroll
            for (int off = 1; off < 16; off <<= 1) sum += __shfl_xor(sum, off);
            float inv = 1.f / sum;
            int row = rows0 + (quad << 2) + r;
            #pragma unroll
            for (int ni = 0; ni < 7; ++ni)
                P[row * LDP + (ni << 4) + l16] = (short)f2bf(sc[ni][r] * inv);
            P[row * LDP + 112 + l16] = 0;        // zero K-pad cols 112..127
        }
        __syncthreads();

        // ---- O = P V  (K=128)
        f32x4 oa[4];
        #pragma unroll
        for (int ni = 0; ni < 4; ++ni) oa[ni] = z;
        #pragma unroll
        for (int ks = 0; ks < 4; ++ks) {
            bf16x8 ap = *(const bf16x8*)&P[(rows0 + l16) * LDP + (ks << 5) + (quad << 3)];
            bf16x8 bv[4];
            #pragma unroll
            for (int ni = 0; ni < 4; ++ni)
                bv[ni] = *(const bf16x8*)&VT[((ni << 4) + l16) * LDV + (ks << 5) + (quad << 3)];
            #pragma unroll
            for (int ni = 0; ni < 4; ++ni)
                oa[ni] = __builtin_amdgcn_mfma_f32_16x16x32_bf16(ap, bv[ni], oa[ni], 0, 0, 0);
        }
        #pragma unroll
        for (int r = 0; r < 4; ++r) {
            int row = rows0 + (quad << 2) + r;
            if (row < NS) {
                u16* orow = O + (rowbase + row) * 512 + (h << 6);
                #pragma unroll
                for (int ni = 0; ni < 4; ++ni)
                    orow[(ni << 4) + l16] = f2bf(oa[ni][r]);
            }
        }
        __syncthreads();   // before next head rewrites Qs/KS/VT (over P)
    }
}

// ---------------------------------------------------------------------------
// Generic bf16 GEMM (used for FFN1): 128x128 tile, BK=32.
// ---------------------------------------------------------------------------
template<int OUTMODE, bool RELU>
__global__ __launch_bounds__(256) void gemm_bf16(
    const u16* __restrict__ A, const u16* __restrict__ W,
    const float* __restrict__ bias, void* __restrict__ Cv, int K, int ldc)
{
    __shared__ short As[128 * 32];
    __shared__ short Bs[128 * 32];
    int t = threadIdx.x;
    int lane = t & 63, wave = t >> 6;
    int quad = lane >> 4, l16 = lane & 15;
    int wr = wave >> 1, wc = wave & 1;
    int m0 = blockIdx.y << 7, n0 = blockIdx.x << 7;

    f32x4 acc[4][4];
    f32x4 z = {0.f, 0.f, 0.f, 0.f};
    #pragma unroll
    for (int mi = 0; mi < 4; ++mi)
        #pragma unroll
        for (int ni = 0; ni < 4; ++ni) acc[mi][ni] = z;

    int rowA = t >> 2;
    int cch = (t & 3) << 3;
    const u16* aSrc0 = A + (size_t)(m0 + rowA) * K + cch;
    const u16* aSrc1 = A + (size_t)(m0 + rowA + 64) * K + cch;
    const u16* bSrc0 = W + (size_t)(n0 + rowA) * K + cch;
    const u16* bSrc1 = W + (size_t)(n0 + rowA + 64) * K + cch;
    short* aDst0 = As + t * 8;
    short* aDst1 = As + (t + 256) * 8;
    short* bDst0 = Bs + t * 8;
    short* bDst1 = Bs + (t + 256) * 8;

    int nk = K >> 5;
    for (int kc = 0; kc < nk; ++kc) {
        if (kc) __syncthreads();
        gload16(aSrc0, aDst0);
        gload16(aSrc1, aDst1);
        gload16(bSrc0, bDst0);
        gload16(bSrc1, bDst1);
        aSrc0 += 32; aSrc1 += 32; bSrc0 += 32; bSrc1 += 32;
        __syncthreads();

        bf16x8 af[4], bw[4];
        #pragma unroll
        for (int mi = 0; mi < 4; ++mi)
            af[mi] = *(const bf16x8*)(As + ((size_t)((wr << 6) + (mi << 4) + l16) * 32 + (quad << 3)));
        #pragma unroll
        for (int ni = 0; ni < 4; ++ni)
            bw[ni] = *(const bf16x8*)(Bs + ((size_t)((wc << 6) + (ni << 4) + l16) * 32 + (quad << 3)));
        #pragma unroll
        for (int mi = 0; mi < 4; ++mi)
            #pragma unroll
            for (int ni = 0; ni < 4; ++ni)
                acc[mi][ni] = __builtin_amdgcn_mfma_f32_16x16x32_bf16(af[mi], bw[ni], acc[mi][ni], 0, 0, 0);
    }

    #pragma unroll
    for (int mi = 0; mi < 4; ++mi) {
        #pragma unroll
        for (int r = 0; r < 4; ++r) {
            int row = m0 + (wr << 6) + (mi << 4) + (quad << 2) + r;
            #pragma unroll
            for (int ni = 0; ni < 4; ++ni) {
                int col = n0 + (wc << 6) + (ni << 4) + l16;
                float v = acc[mi][ni][r];
                if (bias) v += bias[col];
                if (RELU) v = fmaxf(v, 0.f);
                if (OUTMODE == 0)
                    ((float*)Cv)[(size_t)row * ldc + col] = v;
                else
                    ((u16*)Cv)[(size_t)row * ldc + col] = f2bf(v);
            }
        }
    }
}

// ---------------------------------------------------------------------------
// Fused GEMM + add-LayerNorm epilogue (proven R6-R10).
// ---------------------------------------------------------------------------
template<int OUTMODE>
__global__ __launch_bounds__(512, 2) void gemm_ln(
    const u16* __restrict__ A, const u16* __restrict__ W,
    const float* __restrict__ bias, const float* __restrict__ lnw,
    const float* __restrict__ lnb, void* __restrict__ outv, int K)
{
    __shared__ short As[64 * 32];
    __shared__ short Bs[512 * 32];
    __shared__ float red_s[64][9];
    __shared__ float red_q[64][9];
    __shared__ float mrow[64], rrow[64];

    int t = threadIdx.x;
    int lane = t & 63, wave = t >> 6;
    int quad = lane >> 4, l16 = lane & 15;
    int m0 = blockIdx.x << 6;

    f32x4 acc[4][4];
    f32x4 z = {0.f, 0.f, 0.f, 0.f};
    #pragma unroll
    for (int mi = 0; mi < 4; ++mi)
        #pragma unroll
        for (int ni = 0; ni < 4; ++ni) acc[mi][ni] = z;

    int koff = (t & 3) << 3;
    const u16* aSrc = A + (size_t)(m0 + (t >> 2)) * K + koff;
    const u16* bSrc0 = W + (size_t)(t >> 2) * K + koff;
    const u16* bSrc1 = W + (size_t)((t >> 2) + 128) * K + koff;
    const u16* bSrc2 = W + (size_t)((t >> 2) + 256) * K + koff;
    const u16* bSrc3 = W + (size_t)((t >> 2) + 384) * K + koff;
    short* aDst = As + t * 8;
    short* bDst0 = Bs + t * 8;
    short* bDst1 = Bs + (t + 512) * 8;
    short* bDst2 = Bs + (t + 1024) * 8;
    short* bDst3 = Bs + (t + 1536) * 8;

    int nk = K >> 5;
    for (int kc = 0; kc < nk; ++kc) {
        if (kc) __syncthreads();
        if (t < 256) gload16(aSrc, aDst);
        gload16(bSrc0, bDst0);
        gload16(bSrc1, bDst1);
        gload16(bSrc2, bDst2);
        gload16(bSrc3, bDst3);
        aSrc += 32; bSrc0 += 32; bSrc1 += 32; bSrc2 += 32; bSrc3 += 32;
        __syncthreads();

        bf16x8 af[4], bw[4];
        #pragma unroll
        for (int mi = 0; mi < 4; ++mi)
            af[mi] = *(const bf16x8*)(As + ((mi << 4) + l16) * 32 + (quad << 3));
        #pragma unroll
        for (int ni = 0; ni < 4; ++ni)
            bw[ni] = *(const bf16x8*)(Bs + ((wave << 6) + (ni << 4) + l16) * 32 + (quad << 3));
        #pragma unroll
        for (int mi = 0; mi < 4; ++mi)
            #pragma unroll
            for (int ni = 0; ni < 4; ++ni)
                acc[mi][ni] = __builtin_amdgcn_mfma_f32_16x16x32_bf16(af[mi], bw[ni], acc[mi][ni], 0, 0, 0);
    }

    float lwv[4], lbv[4];
    #pragma unroll
    for (int ni = 0; ni < 4; ++ni) {
        int col = (wave << 6) + (ni << 4) + l16;
        float bv = bias[col];
        lwv[ni] = lnw[col];
        lbv[ni] = lnb[col];
        #pragma unroll
        for (int mi = 0; mi < 4; ++mi)
            #pragma unroll
            for (int r = 0; r < 4; ++r) acc[mi][ni][r] += bv;
    }
    #pragma unroll
    for (int mi = 0; mi < 4; ++mi) {
        #pragma unroll
        for (int r = 0; r < 4; ++r) {
            float s = acc[mi][0][r] + acc[mi][1][r] + acc[mi][2][r] + acc[mi][3][r];
            float q = acc[mi][0][r]*acc[mi][0][r] + acc[mi][1][r]*acc[mi][1][r]
                    + acc[mi][2][r]*acc[mi][2][r] + acc[mi][3][r]*acc[mi][3][r];
            #pragma unroll
            for (int off = 1; off < 16; off <<= 1) {
                s += __shfl_xor(s, off);
                q += __shfl_xor(q, off);
            }
            if (l16 == 0) {
                int row = (mi << 4) + (quad << 2) + r;
                red_s[row][wave] = s;
                red_q[row][wave] = q;
            }
        }
    }
    __syncthreads();
    if (t < 64) {
        float s = 0.f, q = 0.f;
        #pragma unroll
        for (int w8 = 0; w8 < 8; ++w8) { s += red_s[t][w8]; q += red_q[t][w8]; }
        float mean = s * (1.f / 512.f);
        float var = q * (1.f / 512.f) - mean * mean;
        mrow[t] = mean;
        rrow[t] = rsqrtf(var + 1e-5f);
    }
    __syncthreads();
    #pragma unroll
    for (int mi = 0; mi < 4; ++mi) {
        #pragma unroll
        for (int r = 0; r < 4; ++r) {
            int lrow = (mi << 4) + (quad << 2) + r;
            float mean = mrow[lrow], rstd = rrow[lrow];
            size_t grow = (size_t)(m0 + lrow) * 512;
            #pragma unroll
            for (int ni = 0; ni < 4; ++ni) {
                int col = (wave << 6) + (ni << 4) + l16;
                float v = acc[mi][ni][r];
                float y = v + (v - mean) * rstd * lwv[ni] + lbv[ni];
                if (OUTMODE == 0) ((float*)outv)[grow + col] = y;
                else ((u16*)outv)[grow + col] = f2bf(y);
            }
        }
    }
}

// ---------------------------------------------------------------------------
// u_stage1: T1[b,r] = dot(Wt[r,:], Y2[b, last, :])    (Y2 bf16)
// ---------------------------------------------------------------------------
__global__ __launch_bounds__(256) void u_stage1_kernel(
    const u16* __restrict__ Y2, const float* __restrict__ Wt,
    float* __restrict__ T1)
{
    __shared__ float yl[16][512];
    int t = threadIdx.x;
    int r0 = blockIdx.x << 6;
    int bg = blockIdx.y << 4;
    for (int l = t; l < 1024; l += 256) {
        int bb = l >> 6, seg = (l & 63) << 3;
        u16x8 v = *(const u16x8*)&Y2[((size_t)(bg + bb) * NS + 99) * ND + seg];
        #pragma unroll
        for (int j = 0; j < 8; ++j) yl[bb][seg + j] = bf2f(v[j]);
    }
    __syncthreads();
    int r = r0 + (t & 63);
    int b0 = t >> 6;
    const float* wr = Wt + (size_t)r * ND;
    float acc[4] = {0.f, 0.f, 0.f, 0.f};
    for (int d = 0; d < ND; d += 4) {
        float4 w4 = *(const float4*)(wr + d);
        #pragma unroll
        for (int bb = 0; bb < 4; ++bb) {
            int bl = (b0 << 2) + bb;
            acc[bb] += w4.x * yl[bl][d] + w4.y * yl[bl][d+1]
                     + w4.z * yl[bl][d+2] + w4.w * yl[bl][d+3];
        }
    }
    #pragma unroll
    for (int bb = 0; bb < 4; ++bb)
        T1[(size_t)(bg + (b0 << 2) + bb) * ND + r] = acc[bb];
}

__global__ __launch_bounds__(256) void u_stage2_kernel(
    const float* __restrict__ T1, const float* __restrict__ Wt,
    float* __restrict__ U)
{
    __shared__ float t1s[16][512];
    int t = threadIdx.x;
    int c0 = blockIdx.x << 6;
    int bg = blockIdx.y << 4;
    for (int l = t; l < 2048; l += 256) {
        int bb = l >> 7, seg = (l & 127) << 2;
        *(float4*)&t1s[bb][seg] = *(const float4*)&T1[(size_t)(bg + bb) * ND + seg];
    }
    __syncthreads();
    int c = c0 + (t & 63);
    int b0 = t >> 6;
    float acc[4] = {0.f, 0.f, 0.f, 0.f};
    for (int r = 0; r < ND; ++r) {
        float w = Wt[(size_t)r * ND + c];
        #pragma unroll
        for (int bb = 0; bb < 4; ++bb)
            acc[bb] += w * t1s[(b0 << 2) + bb][r];
    }
    #pragma unroll
    for (int bb = 0; bb < 4; ++bb)
        U[(size_t)(bg + (b0 << 2) + bb) * ND + c] = acc[bb];
}

// ---------------------------------------------------------------------------
// pool (Y2 bf16)
// ---------------------------------------------------------------------------
__global__ __launch_bounds__(256) void pool_kernel(
    const u16* __restrict__ Y2, const float* __restrict__ U,
    const float* __restrict__ Wout, const float* __restrict__ bout,
    float* __restrict__ out)
{
    __shared__ float u[ND];
    __shared__ float lam[128];
    __shared__ float red[4];
    int t = threadIdx.x;
    int b = blockIdx.x;
    const u16* y2b = Y2 + (size_t)b * NS * ND;
    u[t] = U[(size_t)b * ND + t];
    u[t + 256] = U[(size_t)b * ND + t + 256];
    __syncthreads();
    int wid = t >> 6, lane = t & 63;
    int c0 = lane << 2;
    for (int s = wid; s < NS; s += 4) {
        const u16* yr = y2b + (size_t)s * ND;
        ushort4 q0 = *(const ushort4*)(yr + c0);
        ushort4 q1 = *(const ushort4*)(yr + 256 + c0);
        float a = bf2f(q0.x)*u[c0] + bf2f(q0.y)*u[c0+1] + bf2f(q0.z)*u[c0+2] + bf2f(q0.w)*u[c0+3]
                + bf2f(q1.x)*u[256+c0] + bf2f(q1.y)*u[256+c0+1]
                + bf2f(q1.z)*u[256+c0+2] + bf2f(q1.w)*u[256+c0+3];
        #pragma unroll
        for (int off = 32; off > 0; off >>= 1) a += __shfl_xor(a, off);
        if (lane == 0) lam[s] = a;
    }
    __syncthreads();
    if (t < 64) {
        float l0 = lam[t];
        float l1 = (t + 64 < NS) ? lam[t + 64] : -3.0e38f;
        float mx = fmaxf(l0, l1);
        #pragma unroll
        for (int off = 32; off > 0; off >>= 1) mx = fmaxf(mx, __shfl_xor(mx, off));
        float e0 = expf(l0 - mx);
        float e1 = (t + 64 < NS) ? expf(l1 - mx) : 0.f;
        float ssum = e0 + e1;
        #pragma unroll
        for (int off = 32; off > 0; off >>= 1) ssum += __shfl_xor(ssum, off);
        float inv = 1.f / ssum;
        lam[t] = e0 * inv;
        if (t + 64 < NS) lam[t + 64] = e1 * inv;
    }
    __syncthreads();
    float p0 = 0.f, p1 = 0.f;
    for (int s = 0; s < NS; ++s) {
        float lm = lam[s];
        const u16* yr = y2b + (size_t)s * ND;
        p0 += lm * bf2f(yr[t]);
        p1 += lm * bf2f(yr[t + 256]);
    }
    float vd = p0 * Wout[t] + p1 * Wout[t + 256];
    #pragma unroll
    for (int off = 32; off > 0; off >>= 1) vd += __shfl_xor(vd, off);
    if (lane == 0) red[wid] = vd;
    __syncthreads();
    if (t == 0) out[b] = red[0] + red[1] + red[2] + red[3] + bout[0];
}

// ---------------------------------------------------------------------------
static size_t ws_need(int CBc) {
    size_t cm = (size_t)CBc * NS;
    size_t b = 0;
    b += cm * 512 * 2;         // AO16
    b += cm * 512 * 2;         // Y116
    b += cm * 256 * 2;         // ACT16
    b += cm * 512 * 2;         // Y2 (bf16)
    b += (size_t)CBc * 512 * 4 * 2;  // T1, U
    b += 1536 * 160 * 2;       // Wf
    b += 512 * 512 * 2 + 256 * 512 * 2 + 512 * 256 * 2;
    b += 3 * 8 * 100 * 64 * 4; // T4
    b += 256 * 4;
    b += 64 * 1024;
    return b;
}

extern "C" void kernel_launch(void* const* d_in, const int* in_sizes, int n_in,
                              void* d_out, int out_size, void* d_ws, size_t ws_size,
                              hipStream_t stream)
{
    const float* src   = (const float*)d_in[0];
    const float* Wfeat = (const float*)d_in[1];
    const float* bfeat = (const float*)d_in[2];
    const float* pe    = (const float*)d_in[3];
    const float* Wq    = (const float*)d_in[4];
    const float* bq    = (const float*)d_in[5];
    const float* Wk    = (const float*)d_in[6];
    const float* bk    = (const float*)d_in[7];
    const float* Wv    = (const float*)d_in[8];
    const float* bv    = (const float*)d_in[9];
    const float* Wo    = (const float*)d_in[10];
    const float* bo    = (const float*)d_in[11];
    const float* lnw   = (const float*)d_in[12];
    const float* lnb   = (const float*)d_in[13];
    const float* W1    = (const float*)d_in[14];
    const float* b1    = (const float*)d_in[15];
    const float* W2    = (const float*)d_in[16];
    const float* b2    = (const float*)d_in[17];
    const float* Wt    = (const float*)d_in[18];
    const float* Wout  = (const float*)d_in[19];
    const float* bout  = (const float*)d_in[20];
    float* out = (float*)d_out;

    int CBc = (ws_size >= ws_need(1024)) ? 1024
            : (ws_size >= ws_need(512))  ? 512
            : (ws_size >= ws_need(256))  ? 256 : 128;
    int NCH = NB / CBc;
    size_t CMc = (size_t)CBc * NS;

    char* p = (char*)d_ws;
    auto alloc = [&](size_t bytes) { char* r = p; p += (bytes + 255) & ~(size_t)255; return r; };
    u16*   AO16  = (u16*)  alloc(CMc * 512 * 2);
    u16*   Y116  = (u16*)  alloc(CMc * 512 * 2);
    u16*   ACT16 = (u16*)  alloc(CMc * 256 * 2);
    u16*   Y2    = (u16*)  alloc(CMc * 512 * 2);
    float* T1    = (float*)alloc((size_t)CBc * 512 * 4);
    float* U     = (float*)alloc((size_t)CBc * 512 * 4);
    u16*   Wf    = (u16*)  alloc(1536 * 160 * 2);
    u16*   Wo16  = (u16*)  alloc(512 * 512 * 2);
    u16*   W116  = (u16*)  alloc(256 * 512 * 2);
    u16*   W216  = (u16*)  alloc(512 * 256 * 2);
    float* T4    = (float*)alloc(3 * 8 * 100 * 64 * 4);
    float* b1p   = (float*)alloc(256 * 4);

    prep_w_kernel<<<1536, 256, 0, stream>>>(Wq, Wk, Wv, Wfeat, Wf);
    prep_c_kernel<<<300, 256, 0, stream>>>(Wq, Wk, Wv, bq, bk, bv, bfeat, pe, T4);
    pad_cast_kernel<<<(512 * 512) / 256, 256, 0, stream>>>(Wo, Wo16, 512, 512, 512, 512 * 512);
    pad_cast_kernel<<<(256 * 512) / 256, 256, 0, stream>>>(W1, W116, NF, 512, 512, 256 * 512);
    pad_cast_kernel<<<(512 * 256) / 256, 256, 0, stream>>>(W2, W216, 512, NF, 256, 512 * 256);
    pad_b1_kernel<<<1, 256, 0, stream>>>(b1, b1p);

    dim3 g256(2, CMc / 128);
    dim3 gU(8, CBc / 16);
    int gLN = CMc / 64;

    for (int c = 0; c < NCH; ++c) {
        const float* srcC = src + (size_t)c * CMc * NF;
        float* outC = out + (size_t)c * CBc;

        // fused QKV + attention -> AO16 (bf16)
        qkv_attn_kernel<<<CBc, 512, 0, stream>>>(srcC, Wf, T4, AO16);
        // y1 = (AO16@Wo^T + bo) + LN(...) -> bf16 (fused)
        gemm_ln<1><<<gLN, 512, 0, stream>>>(AO16, Wo16, bo, lnw, lnb, Y116, 512);
        // act = relu(y1 @ W116^T + b1p) -> bf16 [CMc,256]
        gemm_bf16<1, true><<<g256, 256, 0, stream>>>(Y116, W116, b1p, ACT16, 512, 256);
        // y2 = (act@W2^T + b2) + LN(...) -> bf16 (fused)
        gemm_ln<1><<<gLN, 512, 0, stream>>>(ACT16, W216, b2, lnw, lnb, Y2, 256);
        // pooling head
        u_stage1_kernel<<<gU, 256, 0, stream>>>(Y2, Wt, T1);
        u_stage2_kernel<<<gU, 256, 0, stream>>>(T1, Wt, U);
        pool_kernel<<<CBc, 256, 0, stream>>>(Y2, U, Wout, bout, outC);
    }

    (void)in_sizes; (void)n_in; (void)out_size; (void)ws_size;
}